// Round 19
// baseline (386.256 us; speedup 1.0000x reference)
//
#include <hip/hip_runtime.h>
#include <hip/hip_fp16.h>
#include <cstdint>
#include <cstddef>

#define BATCH 16
#define CH 64
#define HWN 65536
#define NBLK 64          // blocks per batch in proj_s (1024 px each)
#define PAD 72           // ushort row stride (144 B = 16B-aligned)

typedef __attribute__((ext_vector_type(8))) _Float16 half8;
typedef __attribute__((ext_vector_type(4))) float f32x4;

// ---------------- workspace layout (bytes) ----------------
static const size_t SP_OFF = 0;
static const size_t ZP_OFF = SP_OFF + (size_t)BATCH * NBLK * 4096 * 4;
static const size_t M_OFF  = ZP_OFF + (size_t)BATCH * NBLK * 4 * 64 * 4;

__device__ __forceinline__ half8 load_frag_f32(const float* p) {
    const float4 w0 = *(const float4*)p;
    const float4 w1 = *(const float4*)(p + 4);
    half8 f;
    f[0] = (_Float16)w0.x; f[1] = (_Float16)w0.y;
    f[2] = (_Float16)w0.z; f[3] = (_Float16)w0.w;
    f[4] = (_Float16)w1.x; f[5] = (_Float16)w1.y;
    f[6] = (_Float16)w1.z; f[7] = (_Float16)w1.w;
    return f;
}

__device__ __forceinline__ uint pack2h(float a, float b) {
    return (uint)__half_as_ushort(__float2half(a)) |
           ((uint)__half_as_ushort(__float2half(b)) << 16);
}

// xt staging swizzle: s(px) = ((px>>3)&7)<<3 (ushort-index XOR on 8-ch blocks)
// 8-aligned XOR preserves b128 read contiguity AND in-fragment channel order.

// ---------------------------------------------------------------------------
// proj_s: theta/phi projections + S-GEMM + Z, 64-px chunks.
// (unchanged from R15/R17 — validated: prefetch + swizzled staging)
// ---------------------------------------------------------------------------
__global__ __launch_bounds__(256) void proj_s(
    const float* __restrict__ x,
    const float* __restrict__ thw, const float* __restrict__ thb,
    const float* __restrict__ phw, const float* __restrict__ phb,
    float* __restrict__ Sp, float* __restrict__ Zp)
{
    __shared__ __align__(16) ushort xt[64 * PAD];   // 9.2 KB  [px][ch^s]
    __shared__ __align__(16) ushort El[64 * PAD];   // 9.2 KB  [ch][px]
    __shared__ __align__(16) ushort Pl[64 * PAD];   // 9.2 KB  [ch][px]
    const int b   = blockIdx.y;
    const int blk = blockIdx.x;
    const int tid = threadIdx.x;
    const int wid = tid >> 6;
    const int l   = tid & 63;
    const int lr  = l & 15;
    const int lg  = l >> 4;

    half8 Wf[2][4][2];
#pragma unroll
    for (int p = 0; p < 2; p++) {
        const float* wsrc = p ? phw : thw;
#pragma unroll
        for (int ot = 0; ot < 4; ot++)
#pragma unroll
            for (int g = 0; g < 2; g++)
                Wf[p][ot][g] = load_frag_f32(wsrc + (ot * 16 + lr) * 64 + g * 32 + lg * 8);
    }
    float bT[16], bP[16];
#pragma unroll
    for (int ot = 0; ot < 4; ot++)
#pragma unroll
        for (int i = 0; i < 4; i++) {
            bT[ot * 4 + i] = thb[ot * 16 + lg * 4 + i];
            bP[ot * 4 + i] = phb[ot * 16 + lg * 4 + i];
        }

    f32x4 Sacc[4];
#pragma unroll
    for (int j = 0; j < 4; j++) Sacc[j] = (f32x4){0.f, 0.f, 0.f, 0.f};
    float z[16];
#pragma unroll
    for (int k = 0; k < 16; k++) z[k] = 0.f;

    const float* xb = x + (size_t)b * CH * HWN;
    const int spx = tid & 63;
    const int chb = (tid >> 6) * 4;
    const int ssw = ((spx >> 3) & 7) << 3;
    ushort* xrow = xt + spx * PAD;

    float xr[4][4];
#pragma unroll
    for (int it = 0; it < 4; it++)
#pragma unroll
        for (int c = 0; c < 4; c++)
            xr[it][c] = xb[(size_t)(chb + 16 * it + c) * HWN + blk * 1024 + spx];

    for (int chk = 0; chk < 16; chk++) {
        const int nb = blk * 1024 + chk * 64;

#pragma unroll
        for (int it = 0; it < 4; it++) {
            uint2 pk;
            pk.x = pack2h(xr[it][0], xr[it][1]);
            pk.y = pack2h(xr[it][2], xr[it][3]);
            *(uint2*)(xrow + ((chb + 16 * it) ^ ssw)) = pk;
        }
        __syncthreads();

        if (chk + 1 < 16) {
            const int nb2 = nb + 64;
#pragma unroll
            for (int it = 0; it < 4; it++)
#pragma unroll
                for (int c = 0; c < 4; c++)
                    xr[it][c] = xb[(size_t)(chb + 16 * it + c) * HWN + nb2 + spx];
        }

        const int ncol = wid * 16 + lr;
        const int rsw  = ((ncol >> 3) & 7) << 3;
        half8 xf0 = *(const half8*)(xt + ncol * PAD + ((lg * 8) ^ rsw));
        half8 xf1 = *(const half8*)(xt + ncol * PAD + ((32 + lg * 8) ^ rsw));
#pragma unroll
        for (int ot = 0; ot < 4; ot++) {
            const int off = (ot * 16 + lg * 4) * PAD + ncol;
            f32x4 acc = {bT[ot * 4 + 0], bT[ot * 4 + 1], bT[ot * 4 + 2], bT[ot * 4 + 3]};
            acc = __builtin_amdgcn_mfma_f32_16x16x32_f16(Wf[0][ot][0], xf0, acc, 0, 0, 0);
            acc = __builtin_amdgcn_mfma_f32_16x16x32_f16(Wf[0][ot][1], xf1, acc, 0, 0, 0);
#pragma unroll
            for (int i = 0; i < 4; i++) {
                float e = __expf(acc[i]);
                z[ot * 4 + i] += e;
                El[off + i * PAD] = __half_as_ushort(__float2half(e));
            }
            f32x4 pcc = {bP[ot * 4 + 0], bP[ot * 4 + 1], bP[ot * 4 + 2], bP[ot * 4 + 3]};
            pcc = __builtin_amdgcn_mfma_f32_16x16x32_f16(Wf[1][ot][0], xf0, pcc, 0, 0, 0);
            pcc = __builtin_amdgcn_mfma_f32_16x16x32_f16(Wf[1][ot][1], xf1, pcc, 0, 0, 0);
#pragma unroll
            for (int i = 0; i < 4; i++)
                Pl[off + i * PAD] = __half_as_ushort(__float2half(pcc[i]));
        }
        __syncthreads();

        const ushort* arow = Pl + (wid * 16 + lr) * PAD;
#pragma unroll
        for (int g = 0; g < 2; g++) {
            const int coff = g * 32 + lg * 8;
            half8 af = *(const half8*)(arow + coff);
#pragma unroll
            for (int j = 0; j < 4; j++) {
                half8 bf = *(const half8*)(El + (j * 16 + lr) * PAD + coff);
                Sacc[j] = __builtin_amdgcn_mfma_f32_16x16x32_f16(af, bf, Sacc[j], 0, 0, 0);
            }
        }
    }

    float* sp = Sp + (size_t)(b * NBLK + blk) * 4096;
#pragma unroll
    for (int j = 0; j < 4; j++)
#pragma unroll
        for (int i = 0; i < 4; i++)
            sp[(wid * 16 + lg * 4 + i) * 64 + j * 16 + lr] = Sacc[j][i];

#pragma unroll
    for (int k = 0; k < 16; k++) {
        float v = z[k];
        v += __shfl_xor(v, 1, 64);
        v += __shfl_xor(v, 2, 64);
        v += __shfl_xor(v, 4, 64);
        v += __shfl_xor(v, 8, 64);
        z[k] = v;
    }
    if (lr == 0) {
        float* zp = Zp + ((size_t)(b * NBLK + blk) * 4 + wid) * 64;
#pragma unroll
        for (int t = 0; t < 4; t++)
#pragma unroll
            for (int i = 0; i < 4; i++)
                zp[t * 16 + lg * 4 + i] = z[t * 4 + i];
    }
}

// ---------------------------------------------------------------------------
// Reduce split-K partials; M[b,c,d] = S[b,c,d] / Z[b,d]   (unchanged)
// ---------------------------------------------------------------------------
__global__ __launch_bounds__(256) void normalize_S(
    const float* __restrict__ Sp, const float* __restrict__ Zp,
    float* __restrict__ M)
{
    const int b   = blockIdx.y;
    const int sl  = blockIdx.x;
    const int tid = threadIdx.x;
    __shared__ float Zl[64];
    if (tid < 64) {
        float s = 0.f;
        const float* zp = Zp + (size_t)b * (NBLK * 4) * 64 + tid;
        for (int k = 0; k < NBLK * 4; k++) s += zp[(size_t)k * 64];
        Zl[tid] = 1.0f / s;
    }
    __syncthreads();
    const float* sp = Sp + (size_t)b * NBLK * 4096;
    float* mp = M + (size_t)b * 4096;
#pragma unroll
    for (int h = 0; h < 2; h++) {
        const int idx = sl * 512 + h * 256 + tid;
        float s = 0.f;
        for (int k = 0; k < NBLK; k++) s += sp[(size_t)k * 4096 + idx];
        mp[idx] = s * Zl[idx & 63];
    }
}

// ---------------------------------------------------------------------------
// attn: barrier-free (R18) with 256-px chunks (4/block, was 8x128). Each
// channel's per-chunk HBM read becomes 1 KB contiguous (was 512 B) — tests
// the DRAM burst-length hypothesis. Wave owns px rows [wid*64,(wid+1)*64);
// lane owns one px/chunk, stages all 64 ch (16 x {4 strided dwords -> b64
// swizzled write}, 256 B/instr). Phase A/B loop nt=0..3. Per-pixel math
// identical to R15-R18 -> absmax unchanged.
// ---------------------------------------------------------------------------
__global__ __launch_bounds__(256) void attn_mfma(
    const float* __restrict__ x,
    const float* __restrict__ gw, const float* __restrict__ gb,
    const float* __restrict__ M,
    float* __restrict__ out)
{
    __shared__ __align__(16) ushort xe[256 * PAD];   // 36.9 KB [px][*]
    const int b   = blockIdx.y;
    const int tid = threadIdx.x;
    const int wid = tid >> 6;
    const int l   = tid & 63;
    const int lr  = l & 15;
    const int lg  = l >> 4;

    const float* xb = x + (size_t)b * CH * HWN;
    float* outb = out + (size_t)b * CH * HWN;

    half8 Gf[4][2];
#pragma unroll
    for (int ot = 0; ot < 4; ot++)
#pragma unroll
        for (int kg = 0; kg < 2; kg++)
            Gf[ot][kg] = load_frag_f32(gw + (ot * 16 + lr) * 64 + kg * 32 + lg * 8);
    float bG[16];
#pragma unroll
    for (int ot = 0; ot < 4; ot++)
#pragma unroll
        for (int i = 0; i < 4; i++) bG[ot * 4 + i] = gb[ot * 16 + lg * 4 + i];

    half8 Mf[4][2];
    const float* Mb = M + (size_t)b * 4096;
#pragma unroll
    for (int ct = 0; ct < 4; ct++)
#pragma unroll
        for (int kg = 0; kg < 2; kg++)
            Mf[ct][kg] = load_frag_f32(Mb + (ct * 16 + lr) * 64 + kg * 32 + lg * 8);

    // wave-private staging: lane owns one pixel row per chunk
    const int wpx = wid * 64 + l;             // lane's pixel (in 256-px chunk)
    const int wsw = ((wpx >> 3) & 7) << 3;    // swizzle key for row wpx
    ushort* wrow = xe + wpx * PAD;

    for (int chk = 0; chk < 4; chk++) {
        const int nb = blockIdx.x * 1024 + chk * 256;

        // ---- stage (wave-private): 16 x {4 strided dwords -> b64 swz write} ----
#pragma unroll
        for (int it = 0; it < 16; it++) {
            const int ch0 = it * 4;
            const float v0 = xb[(size_t)(ch0 + 0) * HWN + nb + wpx];
            const float v1 = xb[(size_t)(ch0 + 1) * HWN + nb + wpx];
            const float v2 = xb[(size_t)(ch0 + 2) * HWN + nb + wpx];
            const float v3 = xb[(size_t)(ch0 + 3) * HWN + nb + wpx];
            uint2 pk;
            pk.x = pack2h(v0, v1);
            pk.y = pack2h(v2, v3);
            *(uint2*)(wrow + (ch0 ^ wsw)) = pk;
        }
        // no barrier: rows [wid*64, wid*64+64) written & read only by this wave

        float rz[4];
        // ---- phase A: frags from xe (swz) -> gy -> softmax -> e into xe ----
#pragma unroll
        for (int nt = 0; nt < 4; nt++) {
            const int ncol = wid * 64 + nt * 16 + lr;
            const int rsw  = ((ncol >> 3) & 7) << 3;
            half8 xf0 = *(const half8*)(xe + ncol * PAD + ((lg * 8) ^ rsw));
            half8 xf1 = *(const half8*)(xe + ncol * PAD + ((32 + lg * 8) ^ rsw));

            float gy[4][4];
#pragma unroll
            for (int ot = 0; ot < 4; ot++) {
                f32x4 acc = {bG[ot * 4 + 0], bG[ot * 4 + 1], bG[ot * 4 + 2], bG[ot * 4 + 3]};
                acc = __builtin_amdgcn_mfma_f32_16x16x32_f16(Gf[ot][0], xf0, acc, 0, 0, 0);
                acc = __builtin_amdgcn_mfma_f32_16x16x32_f16(Gf[ot][1], xf1, acc, 0, 0, 0);
#pragma unroll
                for (int i = 0; i < 4; i++) gy[ot][i] = acc[i];
            }
            float m = gy[0][0];
#pragma unroll
            for (int ot = 0; ot < 4; ot++)
#pragma unroll
                for (int i = 0; i < 4; i++) m = fmaxf(m, gy[ot][i]);
            m = fmaxf(m, __shfl_xor(m, 16, 64));
            m = fmaxf(m, __shfl_xor(m, 32, 64));

            float zs = 0.f;
            ushort* erow = xe + ncol * PAD;   // overwrite own row (x consumed)
#pragma unroll
            for (int ot = 0; ot < 4; ot++) {
                float e0 = __expf(gy[ot][0] - m);
                float e1 = __expf(gy[ot][1] - m);
                float e2 = __expf(gy[ot][2] - m);
                float e3 = __expf(gy[ot][3] - m);
                zs += e0 + e1 + e2 + e3;
                uint2 pk;
                pk.x = pack2h(e0, e1);
                pk.y = pack2h(e2, e3);
                *(uint2*)(erow + ot * 16 + lg * 4) = pk;
            }
            zs += __shfl_xor(zs, 16, 64);
            zs += __shfl_xor(zs, 32, 64);
            rz[nt] = 1.0f / zs;
        }

        // ---- phase B: att = M @ e; 1/Z; residual (L2-hot f32); lrelu ----
#pragma unroll
        for (int nt = 0; nt < 4; nt++) {
            const int ncol = wid * 64 + nt * 16 + lr;
            const ushort* brow = xe + ncol * PAD;      // wave-private row
            half8 bf0 = *(const half8*)(brow + lg * 8);
            half8 bf1 = *(const half8*)(brow + 32 + lg * 8);
            const float sc = rz[nt];
#pragma unroll
            for (int ct = 0; ct < 4; ct++) {
                f32x4 acc = {0.f, 0.f, 0.f, 0.f};
                acc = __builtin_amdgcn_mfma_f32_16x16x32_f16(Mf[ct][0], bf0, acc, 0, 0, 0);
                acc = __builtin_amdgcn_mfma_f32_16x16x32_f16(Mf[ct][1], bf1, acc, 0, 0, 0);
#pragma unroll
                for (int i = 0; i < 4; i++) {
                    const size_t off = (size_t)(ct * 16 + lg * 4 + i) * HWN + nb + ncol;
                    float v = xb[off] + acc[i] * sc;
                    outb[off] = (v >= 0.f) ? v : 0.1f * v;
                }
            }
        }
        // no barrier: next chunk's stage writes only this wave's own rows
    }
}

// ---------------------------------------------------------------------------
extern "C" void kernel_launch(void* const* d_in, const int* in_sizes, int n_in,
                              void* d_out, int out_size, void* d_ws, size_t ws_size,
                              hipStream_t stream)
{
    const float* x   = (const float*)d_in[0];
    const float* gw  = (const float*)d_in[1];
    const float* gb  = (const float*)d_in[2];
    const float* thw = (const float*)d_in[3];
    const float* thb = (const float*)d_in[4];
    const float* phw = (const float*)d_in[5];
    const float* phb = (const float*)d_in[6];
    float* out = (float*)d_out;

    char* ws = (char*)d_ws;
    float* Sp = (float*)(ws + SP_OFF);
    float* Zp = (float*)(ws + ZP_OFF);
    float* M  = (float*)(ws + M_OFF);

    dim3 blk(256);
    proj_s<<<dim3(NBLK, BATCH), blk, 0, stream>>>(x, thw, thb, phw, phb, Sp, Zp);
    normalize_S<<<dim3(8, BATCH), blk, 0, stream>>>(Sp, Zp, M);
    attn_mfma<<<dim3(HWN / 1024, BATCH), blk, 0, stream>>>(x, gw, gb, M, out);
}

// Round 20
// 247.693 us; speedup vs baseline: 1.5594x; 1.5594x over previous
//
#include <hip/hip_runtime.h>
#include <hip/hip_fp16.h>
#include <cstdint>
#include <cstddef>

#define BATCH 16
#define CH 64
#define HWN 65536
#define NBLK 64          // blocks per batch in proj_s (1024 px each)
#define PAD 72           // ushort row stride (144 B = 16B-aligned)
#define ACHUNK 8         // chunks (128 px) per attn block -> 1024 px/block

typedef __attribute__((ext_vector_type(8))) _Float16 half8;
typedef __attribute__((ext_vector_type(4))) float f32x4;

// ---------------- workspace layout (bytes) ----------------
static const size_t SP_OFF = 0;
static const size_t ZP_OFF = SP_OFF + (size_t)BATCH * NBLK * 4096 * 4;
static const size_t M_OFF  = ZP_OFF + (size_t)BATCH * NBLK * 4 * 64 * 4;

__device__ __forceinline__ half8 load_frag_f32(const float* p) {
    const float4 w0 = *(const float4*)p;
    const float4 w1 = *(const float4*)(p + 4);
    half8 f;
    f[0] = (_Float16)w0.x; f[1] = (_Float16)w0.y;
    f[2] = (_Float16)w0.z; f[3] = (_Float16)w0.w;
    f[4] = (_Float16)w1.x; f[5] = (_Float16)w1.y;
    f[6] = (_Float16)w1.z; f[7] = (_Float16)w1.w;
    return f;
}

__device__ __forceinline__ uint pack2h(float a, float b) {
    return (uint)__half_as_ushort(__float2half(a)) |
           ((uint)__half_as_ushort(__float2half(b)) << 16);
}

// xt staging swizzle: s(px) = ((px>>3)&7)<<3 (ushort-index XOR on 8-ch blocks)
// 8-aligned XOR preserves b128 read contiguity AND in-fragment channel order.

// ---------------------------------------------------------------------------
// proj_s: theta/phi projections + S-GEMM + Z, 64-px chunks.
// (R15-validated: T14 prefetch + conflict-free swizzled staging)
// ---------------------------------------------------------------------------
__global__ __launch_bounds__(256) void proj_s(
    const float* __restrict__ x,
    const float* __restrict__ thw, const float* __restrict__ thb,
    const float* __restrict__ phw, const float* __restrict__ phb,
    float* __restrict__ Sp, float* __restrict__ Zp)
{
    __shared__ __align__(16) ushort xt[64 * PAD];   // 9.2 KB  [px][ch^s]
    __shared__ __align__(16) ushort El[64 * PAD];   // 9.2 KB  [ch][px]
    __shared__ __align__(16) ushort Pl[64 * PAD];   // 9.2 KB  [ch][px]
    const int b   = blockIdx.y;
    const int blk = blockIdx.x;
    const int tid = threadIdx.x;
    const int wid = tid >> 6;
    const int l   = tid & 63;
    const int lr  = l & 15;
    const int lg  = l >> 4;

    half8 Wf[2][4][2];
#pragma unroll
    for (int p = 0; p < 2; p++) {
        const float* wsrc = p ? phw : thw;
#pragma unroll
        for (int ot = 0; ot < 4; ot++)
#pragma unroll
            for (int g = 0; g < 2; g++)
                Wf[p][ot][g] = load_frag_f32(wsrc + (ot * 16 + lr) * 64 + g * 32 + lg * 8);
    }
    float bT[16], bP[16];
#pragma unroll
    for (int ot = 0; ot < 4; ot++)
#pragma unroll
        for (int i = 0; i < 4; i++) {
            bT[ot * 4 + i] = thb[ot * 16 + lg * 4 + i];
            bP[ot * 4 + i] = phb[ot * 16 + lg * 4 + i];
        }

    f32x4 Sacc[4];
#pragma unroll
    for (int j = 0; j < 4; j++) Sacc[j] = (f32x4){0.f, 0.f, 0.f, 0.f};
    float z[16];
#pragma unroll
    for (int k = 0; k < 16; k++) z[k] = 0.f;

    const float* xb = x + (size_t)b * CH * HWN;
    const int spx = tid & 63;
    const int chb = (tid >> 6) * 4;
    const int ssw = ((spx >> 3) & 7) << 3;
    ushort* xrow = xt + spx * PAD;

    float xr[4][4];
#pragma unroll
    for (int it = 0; it < 4; it++)
#pragma unroll
        for (int c = 0; c < 4; c++)
            xr[it][c] = xb[(size_t)(chb + 16 * it + c) * HWN + blk * 1024 + spx];

    for (int chk = 0; chk < 16; chk++) {
        const int nb = blk * 1024 + chk * 64;

#pragma unroll
        for (int it = 0; it < 4; it++) {
            uint2 pk;
            pk.x = pack2h(xr[it][0], xr[it][1]);
            pk.y = pack2h(xr[it][2], xr[it][3]);
            *(uint2*)(xrow + ((chb + 16 * it) ^ ssw)) = pk;
        }
        __syncthreads();

        if (chk + 1 < 16) {
            const int nb2 = nb + 64;
#pragma unroll
            for (int it = 0; it < 4; it++)
#pragma unroll
                for (int c = 0; c < 4; c++)
                    xr[it][c] = xb[(size_t)(chb + 16 * it + c) * HWN + nb2 + spx];
        }

        const int ncol = wid * 16 + lr;
        const int rsw  = ((ncol >> 3) & 7) << 3;
        half8 xf0 = *(const half8*)(xt + ncol * PAD + ((lg * 8) ^ rsw));
        half8 xf1 = *(const half8*)(xt + ncol * PAD + ((32 + lg * 8) ^ rsw));
#pragma unroll
        for (int ot = 0; ot < 4; ot++) {
            const int off = (ot * 16 + lg * 4) * PAD + ncol;
            f32x4 acc = {bT[ot * 4 + 0], bT[ot * 4 + 1], bT[ot * 4 + 2], bT[ot * 4 + 3]};
            acc = __builtin_amdgcn_mfma_f32_16x16x32_f16(Wf[0][ot][0], xf0, acc, 0, 0, 0);
            acc = __builtin_amdgcn_mfma_f32_16x16x32_f16(Wf[0][ot][1], xf1, acc, 0, 0, 0);
#pragma unroll
            for (int i = 0; i < 4; i++) {
                float e = __expf(acc[i]);
                z[ot * 4 + i] += e;
                El[off + i * PAD] = __half_as_ushort(__float2half(e));
            }
            f32x4 pcc = {bP[ot * 4 + 0], bP[ot * 4 + 1], bP[ot * 4 + 2], bP[ot * 4 + 3]};
            pcc = __builtin_amdgcn_mfma_f32_16x16x32_f16(Wf[1][ot][0], xf0, pcc, 0, 0, 0);
            pcc = __builtin_amdgcn_mfma_f32_16x16x32_f16(Wf[1][ot][1], xf1, pcc, 0, 0, 0);
#pragma unroll
            for (int i = 0; i < 4; i++)
                Pl[off + i * PAD] = __half_as_ushort(__float2half(pcc[i]));
        }
        __syncthreads();

        const ushort* arow = Pl + (wid * 16 + lr) * PAD;
#pragma unroll
        for (int g = 0; g < 2; g++) {
            const int coff = g * 32 + lg * 8;
            half8 af = *(const half8*)(arow + coff);
#pragma unroll
            for (int j = 0; j < 4; j++) {
                half8 bf = *(const half8*)(El + (j * 16 + lr) * PAD + coff);
                Sacc[j] = __builtin_amdgcn_mfma_f32_16x16x32_f16(af, bf, Sacc[j], 0, 0, 0);
            }
        }
    }

    float* sp = Sp + (size_t)(b * NBLK + blk) * 4096;
#pragma unroll
    for (int j = 0; j < 4; j++)
#pragma unroll
        for (int i = 0; i < 4; i++)
            sp[(wid * 16 + lg * 4 + i) * 64 + j * 16 + lr] = Sacc[j][i];

#pragma unroll
    for (int k = 0; k < 16; k++) {
        float v = z[k];
        v += __shfl_xor(v, 1, 64);
        v += __shfl_xor(v, 2, 64);
        v += __shfl_xor(v, 4, 64);
        v += __shfl_xor(v, 8, 64);
        z[k] = v;
    }
    if (lr == 0) {
        float* zp = Zp + ((size_t)(b * NBLK + blk) * 4 + wid) * 64;
#pragma unroll
        for (int t = 0; t < 4; t++)
#pragma unroll
            for (int i = 0; i < 4; i++)
                zp[t * 16 + lg * 4 + i] = z[t * 4 + i];
    }
}

// ---------------------------------------------------------------------------
// Reduce split-K partials; M[b,c,d] = S[b,c,d] / Z[b,d]   (unchanged)
// ---------------------------------------------------------------------------
__global__ __launch_bounds__(256) void normalize_S(
    const float* __restrict__ Sp, const float* __restrict__ Zp,
    float* __restrict__ M)
{
    const int b   = blockIdx.y;
    const int sl  = blockIdx.x;
    const int tid = threadIdx.x;
    __shared__ float Zl[64];
    if (tid < 64) {
        float s = 0.f;
        const float* zp = Zp + (size_t)b * (NBLK * 4) * 64 + tid;
        for (int k = 0; k < NBLK * 4; k++) s += zp[(size_t)k * 64];
        Zl[tid] = 1.0f / s;
    }
    __syncthreads();
    const float* sp = Sp + (size_t)b * NBLK * 4096;
    float* mp = M + (size_t)b * 4096;
#pragma unroll
    for (int h = 0; h < 2; h++) {
        const int idx = sl * 512 + h * 256 + tid;
        float s = 0.f;
        for (int k = 0; k < NBLK; k++) s += sp[(size_t)k * 4096 + idx];
        mp[idx] = s * Zl[idx & 63];
    }
}

// ---------------------------------------------------------------------------
// attn: R17 exact (best measured, 247.9 µs): 128-px chunks (L2-fit reuse
// distance), El aliased onto xt (one xe buffer, 18.4 KB), 2 barriers/chunk.
// Row-lifetime legality per chunk: after the stage barrier, row px is touched
// only by its owner wave in program order {frag-read -> e-overwrite ->
// phaseB-read}; per-wave DS ops are in-order; nt row ranges disjoint.
// ---------------------------------------------------------------------------
__global__ __launch_bounds__(256) void attn_mfma(
    const float* __restrict__ x,
    const float* __restrict__ gw, const float* __restrict__ gb,
    const float* __restrict__ M,
    float* __restrict__ out)
{
    __shared__ __align__(16) ushort xe[128 * PAD];   // 18.4 KB [px][*]
    const int b   = blockIdx.y;
    const int tid = threadIdx.x;
    const int wid = tid >> 6;
    const int l   = tid & 63;
    const int lr  = l & 15;
    const int lg  = l >> 4;

    const float* xb = x + (size_t)b * CH * HWN;
    float* outb = out + (size_t)b * CH * HWN;

    half8 Gf[4][2];
#pragma unroll
    for (int ot = 0; ot < 4; ot++)
#pragma unroll
        for (int kg = 0; kg < 2; kg++)
            Gf[ot][kg] = load_frag_f32(gw + (ot * 16 + lr) * 64 + kg * 32 + lg * 8);
    float bG[16];
#pragma unroll
    for (int ot = 0; ot < 4; ot++)
#pragma unroll
        for (int i = 0; i < 4; i++) bG[ot * 4 + i] = gb[ot * 16 + lg * 4 + i];

    half8 Mf[4][2];
    const float* Mb = M + (size_t)b * 4096;
#pragma unroll
    for (int ct = 0; ct < 4; ct++)
#pragma unroll
        for (int kg = 0; kg < 2; kg++)
            Mf[ct][kg] = load_frag_f32(Mb + (ct * 16 + lr) * 64 + kg * 32 + lg * 8);

    const int spx0 = tid & 63;
    const int chb  = (tid >> 6) * 4;

    for (int chk = 0; chk < ACHUNK; chk++) {
        const int nb = blockIdx.x * (128 * ACHUNK) + chk * 128;

        // ---- stage x-tile: coalesced dwords -> b64 swizzled writes ----
#pragma unroll
        for (int h = 0; h < 2; h++) {
            const int spx = spx0 + 64 * h;
            const int ssw = ((spx >> 3) & 7) << 3;
            float v[4][4];
#pragma unroll
            for (int it = 0; it < 4; it++)
#pragma unroll
                for (int c = 0; c < 4; c++)
                    v[it][c] = xb[(size_t)(chb + 16 * it + c) * HWN + nb + spx];
            ushort* xrow = xe + spx * PAD;
#pragma unroll
            for (int it = 0; it < 4; it++) {
                uint2 pk;
                pk.x = pack2h(v[it][0], v[it][1]);
                pk.y = pack2h(v[it][2], v[it][3]);
                *(uint2*)(xrow + ((chb + 16 * it) ^ ssw)) = pk;
            }
        }
        __syncthreads();

        float rz[2];
        // ---- phase A: frags from xe (swz) -> gy -> softmax -> e into xe ----
#pragma unroll
        for (int nt = 0; nt < 2; nt++) {
            const int ncol = wid * 32 + nt * 16 + lr;
            const int rsw  = ((ncol >> 3) & 7) << 3;
            half8 xf0 = *(const half8*)(xe + ncol * PAD + ((lg * 8) ^ rsw));
            half8 xf1 = *(const half8*)(xe + ncol * PAD + ((32 + lg * 8) ^ rsw));

            float gy[4][4];
#pragma unroll
            for (int ot = 0; ot < 4; ot++) {
                f32x4 acc = {bG[ot * 4 + 0], bG[ot * 4 + 1], bG[ot * 4 + 2], bG[ot * 4 + 3]};
                acc = __builtin_amdgcn_mfma_f32_16x16x32_f16(Gf[ot][0], xf0, acc, 0, 0, 0);
                acc = __builtin_amdgcn_mfma_f32_16x16x32_f16(Gf[ot][1], xf1, acc, 0, 0, 0);
#pragma unroll
                for (int i = 0; i < 4; i++) gy[ot][i] = acc[i];
            }
            float m = gy[0][0];
#pragma unroll
            for (int ot = 0; ot < 4; ot++)
#pragma unroll
                for (int i = 0; i < 4; i++) m = fmaxf(m, gy[ot][i]);
            m = fmaxf(m, __shfl_xor(m, 16, 64));
            m = fmaxf(m, __shfl_xor(m, 32, 64));

            float zs = 0.f;
            ushort* erow = xe + ncol * PAD;   // overwrite own row (x consumed)
#pragma unroll
            for (int ot = 0; ot < 4; ot++) {
                float e0 = __expf(gy[ot][0] - m);
                float e1 = __expf(gy[ot][1] - m);
                float e2 = __expf(gy[ot][2] - m);
                float e3 = __expf(gy[ot][3] - m);
                zs += e0 + e1 + e2 + e3;
                uint2 pk;
                pk.x = pack2h(e0, e1);
                pk.y = pack2h(e2, e3);
                *(uint2*)(erow + ot * 16 + lg * 4) = pk;
            }
            zs += __shfl_xor(zs, 16, 64);
            zs += __shfl_xor(zs, 32, 64);
            rz[nt] = 1.0f / zs;
        }

        // ---- phase B: att = M @ e; 1/Z; residual (L2-hot f32); lrelu ----
#pragma unroll
        for (int nt = 0; nt < 2; nt++) {
            const int ncol = wid * 32 + nt * 16 + lr;
            const ushort* brow = xe + ncol * PAD;      // wave-private row
            half8 bf0 = *(const half8*)(brow + lg * 8);
            half8 bf1 = *(const half8*)(brow + 32 + lg * 8);
            const float sc = rz[nt];
#pragma unroll
            for (int ct = 0; ct < 4; ct++) {
                f32x4 acc = {0.f, 0.f, 0.f, 0.f};
                acc = __builtin_amdgcn_mfma_f32_16x16x32_f16(Mf[ct][0], bf0, acc, 0, 0, 0);
                acc = __builtin_amdgcn_mfma_f32_16x16x32_f16(Mf[ct][1], bf1, acc, 0, 0, 0);
#pragma unroll
                for (int i = 0; i < 4; i++) {
                    const size_t off = (size_t)(ct * 16 + lg * 4 + i) * HWN + nb + ncol;
                    float v = xb[off] + acc[i] * sc;
                    outb[off] = (v >= 0.f) ? v : 0.1f * v;
                }
            }
        }
        __syncthreads();   // xe safe to rewrite next chunk
    }
}

// ---------------------------------------------------------------------------
extern "C" void kernel_launch(void* const* d_in, const int* in_sizes, int n_in,
                              void* d_out, int out_size, void* d_ws, size_t ws_size,
                              hipStream_t stream)
{
    const float* x   = (const float*)d_in[0];
    const float* gw  = (const float*)d_in[1];
    const float* gb  = (const float*)d_in[2];
    const float* thw = (const float*)d_in[3];
    const float* thb = (const float*)d_in[4];
    const float* phw = (const float*)d_in[5];
    const float* phb = (const float*)d_in[6];
    float* out = (float*)d_out;

    char* ws = (char*)d_ws;
    float* Sp = (float*)(ws + SP_OFF);
    float* Zp = (float*)(ws + ZP_OFF);
    float* M  = (float*)(ws + M_OFF);

    dim3 blk(256);
    proj_s<<<dim3(NBLK, BATCH), blk, 0, stream>>>(x, thw, thb, phw, phb, Sp, Zp);
    normalize_S<<<dim3(8, BATCH), blk, 0, stream>>>(Sp, Zp, M);
    attn_mfma<<<dim3(HWN / (128 * ACHUNK), BATCH), blk, 0, stream>>>(x, gw, gb, M, out);
}